// Round 1
// baseline (178.601 us; speedup 1.0000x reference)
//
#include <hip/hip_runtime.h>
#include <math.h>

#define EPS 1e-6f

struct F3 { float x, y, z; };

__device__ inline F3 sub3(F3 a, F3 b) { return {a.x-b.x, a.y-b.y, a.z-b.z}; }
__device__ inline float dot3(F3 a, F3 b) { return a.x*b.x + a.y*b.y + a.z*b.z; }
__device__ inline F3 scale3(F3 a, float s) { return {a.x*s, a.y*s, a.z*s}; }
__device__ inline F3 cross3(F3 a, F3 b) {
    return {a.y*b.z - a.z*b.y, a.z*b.x - a.x*b.z, a.x*b.y - a.y*b.x};
}
__device__ inline F3 norm3(F3 v) {
    float s = dot3(v, v);
    float inv = 1.0f / sqrtf(fmaxf(s, EPS));
    return scale3(v, inv);
}

// block reduce: returns full sum to thread 0 only. red must hold >= blockDim/64 floats.
__device__ inline float block_reduce_sum(float v, float* red) {
    for (int o = 32; o > 0; o >>= 1) v += __shfl_down(v, o, 64);
    int wave = threadIdx.x >> 6, lane = threadIdx.x & 63;
    int nw = blockDim.x >> 6;
    __syncthreads();
    if (lane == 0) red[wave] = v;
    __syncthreads();
    float s = 0.f;
    if (threadIdx.x == 0) for (int w = 0; w < nw; w++) s += red[w];
    return s;
}

// ---------------- frames ----------------
// idx in [0, L*N): pred frame (l = idx/N, i = idx%N)
// idx in [L*N, (L+1)*N): gt frame i = idx - L*N; also computes maskbits[i]
__global__ __launch_bounds__(256) void frames_kernel(
    const float* __restrict__ pred, const float* __restrict__ gt,
    const float* __restrict__ atom_mask,
    float* __restrict__ framesP, float* __restrict__ framesG,
    int* __restrict__ maskbits, float* __restrict__ acc,
    int L, int N, int A)
{
    int idx = blockIdx.x * blockDim.x + threadIdx.x;
    if (idx == 0) {
        for (int k = 0; k < 8; k++) acc[k] = 0.f;  // zero accumulators (ws is poisoned)
    }
    int total = (L + 1) * N;
    if (idx >= total) return;

    const float* base;
    float* outF;
    if (idx < L * N) {
        base = pred + (size_t)idx * A * 3;
        outF = framesP + (size_t)idx * 12;
    } else {
        int i = idx - L * N;
        base = gt + (size_t)i * A * 3;
        outF = framesG + (size_t)i * 12;
        unsigned m = 0;
        for (int a = 0; a < A; a++)
            if (atom_mask[(size_t)i * A + a] > 0.f) m |= (1u << a);
        maskbits[i] = (int)m;
    }
    F3 n  = {base[0], base[1], base[2]};
    F3 ca = {base[3], base[4], base[5]};
    F3 c  = {base[6], base[7], base[8]};
    F3 e1 = norm3(sub3(c, ca));
    F3 v2 = sub3(n, ca);
    float d = dot3(e1, v2);
    F3 e2 = norm3({v2.x - d*e1.x, v2.y - d*e1.y, v2.z - d*e1.z});
    F3 e3 = cross3(e1, e2);
    outF[0] = e1.x; outF[1] = e1.y; outF[2] = e1.z;
    outF[3] = e2.x; outF[4] = e2.y; outF[5] = e2.z;
    outF[6] = e3.x; outF[7] = e3.y; outF[8] = e3.z;
    outF[9] = ca.x; outF[10] = ca.y; outF[11] = ca.z;
}

// ---------------- fape core ----------------
// block b = (l, i); threads cover j. Fuses the intra/inter/diag reductions.
__global__ __launch_bounds__(256) void fape_kernel(
    const float* __restrict__ pred, const float* __restrict__ gt,
    const int* __restrict__ batch, const int* __restrict__ chain,
    const float* __restrict__ framesP, const float* __restrict__ framesG,
    const int* __restrict__ maskbits,
    float* __restrict__ diag, float* __restrict__ acc,
    float* __restrict__ out_final, float* __restrict__ out_rot,
    int L, int N, int A)
{
    int b = blockIdx.x;
    int l = b / N;
    int i = b - l * N;
    const float* fP = framesP + (size_t)b * 12;
    const float* fG = framesG + (size_t)i * 12;

    // pred frame rows (e1p,e2p,e3p) and ca
    float p00 = fP[0], p01 = fP[1], p02 = fP[2];
    float p10 = fP[3], p11 = fP[4], p12 = fP[5];
    float p20 = fP[6], p21 = fP[7], p22 = fP[8];
    float cpx = fP[9], cpy = fP[10], cpz = fP[11];
    float g00 = fG[0], g01 = fG[1], g02 = fG[2];
    float g10 = fG[3], g11 = fG[4], g12 = fG[5];
    float g20 = fG[6], g21 = fG[7], g22 = fG[8];
    float cgx = fG[9], cgy = fG[10], cgz = fG[11];
    // constant offset: c_k = e_pk . ca_p - e_gk . ca_g
    float c0 = p00*cpx + p01*cpy + p02*cpz - (g00*cgx + g01*cgy + g02*cgz);
    float c1 = p10*cpx + p11*cpy + p12*cpz - (g10*cgx + g11*cgy + g12*cgz);
    float c2 = p20*cpx + p21*cpy + p22*cpz - (g20*cgx + g21*cgy + g22*cgz);

    int mi = maskbits[i];
    int bi = batch[i];
    int ci = chain[i];

    float s_same = 0.f, s_other = 0.f, c_same = 0.f, c_other = 0.f;
    bool last = (l == L - 1);

    for (int j = threadIdx.x; j < N; j += blockDim.x) {
        float fv = 0.f;
        bool pm2 = false, samec = false;
        if (batch[j] == bi) {
            int mj = mi & maskbits[j];
            if (mj) {
                pm2 = true;
                samec = (chain[j] == ci);
                int cnt = __popc((unsigned)mj);
                float num = 0.f;
                const float* xb = pred + (((size_t)l * N + j) * A) * 3;
                const float* yb = gt + ((size_t)j * A) * 3;
                for (int a = 0; a < A; a++) {
                    if (!((mj >> a) & 1)) continue;
                    float x0 = xb[a*3+0], x1 = xb[a*3+1], x2 = xb[a*3+2];
                    float y0 = yb[a*3+0], y1 = yb[a*3+1], y2 = yb[a*3+2];
                    float d0 = p00*x0 + p01*x1 + p02*x2 - (g00*y0 + g01*y1 + g02*y2) - c0;
                    float d1 = p10*x0 + p11*x1 + p12*x2 - (g10*y0 + g11*y1 + g12*y2) - c1;
                    float d2 = p20*x0 + p21*x1 + p22*x2 - (g20*y0 + g21*y1 + g22*y2) - c2;
                    float s = d0*d0 + d1*d1 + d2*d2;
                    num += sqrtf(fmaxf(s, EPS));
                }
                fv = num / (float)cnt;
            }
        }
        if (last) out_final[(size_t)i * N + j] = fv;
        if (j == i) {
            diag[b] = fv;
            if (last) out_rot[i] = fv;
        }
        float cl = fminf(fv, 10.f);
        if (pm2) {
            if (samec) { s_same += cl; c_same += 1.f; }
            else       { s_other += cl; c_other += 1.f; }
        }
    }

    // block reduce 4 values
    for (int o = 32; o > 0; o >>= 1) {
        s_same  += __shfl_down(s_same, o, 64);
        s_other += __shfl_down(s_other, o, 64);
        c_same  += __shfl_down(c_same, o, 64);
        c_other += __shfl_down(c_other, o, 64);
    }
    __shared__ float red[4][4];
    int wave = threadIdx.x >> 6, lane = threadIdx.x & 63;
    if (lane == 0) {
        red[wave][0] = s_same; red[wave][1] = s_other;
        red[wave][2] = c_same; red[wave][3] = c_other;
    }
    __syncthreads();
    if (threadIdx.x == 0) {
        float ss = 0, so = 0, cs = 0, co = 0;
        int nw = blockDim.x >> 6;
        for (int w = 0; w < nw; w++) {
            ss += red[w][0]; so += red[w][1]; cs += red[w][2]; co += red[w][3];
        }
        atomicAdd(&acc[l], ss);
        atomicAdd(&acc[L + l], so);
        if (l == 0) {
            atomicAdd(&acc[2 * L], cs);
            atomicAdd(&acc[2 * L + 1], co);
        }
    }
}

// ---------------- finalize scalars ----------------
__global__ __launch_bounds__(256) void finalize_kernel(
    const int* __restrict__ maskbits, const float* __restrict__ diag,
    const float* __restrict__ acc, float* __restrict__ out, int L, int N)
{
    __shared__ float red[8];
    float nr = 0.f;
    for (int i = threadIdx.x; i < N; i += blockDim.x)
        nr += (maskbits[i] != 0) ? 1.f : 0.f;
    float n_res = block_reduce_sum(nr, red);

    float rs[4];  // assumes L <= 4
    for (int l = 0; l < L; l++) {
        float s = 0.f;
        for (int i = threadIdx.x; i < N; i += blockDim.x)
            s += diag[(size_t)l * N + i];
        rs[l] = block_reduce_sum(s, red);
    }
    if (threadIdx.x == 0) {
        float cs = fmaxf(acc[2 * L], 1e-6f);
        float co = fmaxf(acc[2 * L + 1], 1e-6f);
        float nrm = fmaxf(n_res, 1e-6f);
        for (int l = 0; l < L; l++) {
            out[l]     = acc[l] / cs / 10.f + acc[L + l] / co / 10.f;  // fape_loss
            out[L + l] = rs[l] / nrm;                                   // rotamer_loss
        }
    }
}

// ---------------- lddt ----------------
__global__ __launch_bounds__(256) void lddt_kernel(
    const float* __restrict__ pred, const float* __restrict__ gt,
    const int* __restrict__ maskbits, float* __restrict__ out_lddt,
    int L, int N, int A)
{
    int i = blockIdx.x;
    __shared__ float red[8];
    bool rmi = (maskbits[i] != 0);
    const float* pbase = pred + (((size_t)(L - 1) * N) * A) * 3;  // last layer
    float gx = gt[((size_t)i * A + 1) * 3 + 0];
    float gy = gt[((size_t)i * A + 1) * 3 + 1];
    float gz = gt[((size_t)i * A + 1) * 3 + 2];
    float px = pbase[((size_t)i * A + 1) * 3 + 0];
    float py = pbase[((size_t)i * A + 1) * 3 + 1];
    float pz = pbase[((size_t)i * A + 1) * 3 + 2];

    float suml = 0.f, cnt = 0.f;
    if (rmi) {
        for (int j = threadIdx.x; j < N; j += blockDim.x) {
            if (j == i) continue;
            if (maskbits[j] == 0) continue;
            float dx = gx - gt[((size_t)j * A + 1) * 3 + 0];
            float dy = gy - gt[((size_t)j * A + 1) * 3 + 1];
            float dz = gz - gt[((size_t)j * A + 1) * 3 + 2];
            float gd = sqrtf(fmaxf(dx*dx + dy*dy + dz*dz, EPS));
            if (gd < 15.f) {
                float ex = px - pbase[((size_t)j * A + 1) * 3 + 0];
                float ey = py - pbase[((size_t)j * A + 1) * 3 + 1];
                float ez = pz - pbase[((size_t)j * A + 1) * 3 + 2];
                float pd = sqrtf(fmaxf(ex*ex + ey*ey + ez*ez, EPS));
                float de = fabsf(gd - pd);
                float lv = ((de < 0.5f ? 1.f : 0.f) + (de < 1.f ? 1.f : 0.f) +
                            (de < 2.f ? 1.f : 0.f) + (de < 4.f ? 1.f : 0.f)) * 0.25f;
                suml += lv;
                cnt += 1.f;
            }
        }
    }
    float ts = block_reduce_sum(suml, red);
    float tc = block_reduce_sum(cnt, red);
    if (threadIdx.x == 0) out_lddt[i] = ts / fmaxf(tc, 1e-6f);
}

extern "C" void kernel_launch(void* const* d_in, const int* in_sizes, int n_in,
                              void* d_out, int out_size, void* d_ws, size_t ws_size,
                              hipStream_t stream)
{
    const float* pred      = (const float*)d_in[0];
    const float* gt        = (const float*)d_in[1];
    const float* atom_mask = (const float*)d_in[2];
    const int*   batch     = (const int*)d_in[3];
    const int*   chain     = (const int*)d_in[4];

    int N = in_sizes[3];                 // batch has N elements
    int A = in_sizes[2] / N;             // atom_mask is N*A
    int L = in_sizes[0] / (N * A * 3);   // pred is L*N*A*3

    float* out = (float*)d_out;
    // output layout: fape_loss(L), rotamer_loss(L), final_ae(N*N), rotamer_error[-1](N), lddt(N)
    float* out_final = out + 2 * L;
    float* out_rot   = out_final + (size_t)N * N;
    float* out_lddt  = out_rot + N;

    float* ws = (float*)d_ws;
    float* framesP = ws;                                 // L*N*12
    float* framesG = framesP + (size_t)L * N * 12;       // N*12
    float* diag    = framesG + (size_t)N * 12;           // L*N
    float* acc     = diag + (size_t)L * N;               // 8
    int*   maskbits = (int*)(acc + 8);                   // N

    int totalF = (L + 1) * N;
    frames_kernel<<<(totalF + 255) / 256, 256, 0, stream>>>(
        pred, gt, atom_mask, framesP, framesG, maskbits, acc, L, N, A);
    fape_kernel<<<L * N, 256, 0, stream>>>(
        pred, gt, batch, chain, framesP, framesG, maskbits,
        diag, acc, out_final, out_rot, L, N, A);
    finalize_kernel<<<1, 256, 0, stream>>>(maskbits, diag, acc, out, L, N);
    lddt_kernel<<<N, 256, 0, stream>>>(pred, gt, maskbits, out_lddt, L, N, A);
}

// Round 2
// 162.863 us; speedup vs baseline: 1.0966x; 1.0966x over previous
//
#include <hip/hip_runtime.h>
#include <math.h>

#define EPS 1e-6f

struct F3 { float x, y, z; };

__device__ inline F3 sub3(F3 a, F3 b) { return {a.x-b.x, a.y-b.y, a.z-b.z}; }
__device__ inline float dot3(F3 a, F3 b) { return a.x*b.x + a.y*b.y + a.z*b.z; }
__device__ inline F3 scale3(F3 a, float s) { return {a.x*s, a.y*s, a.z*s}; }
__device__ inline F3 cross3(F3 a, F3 b) {
    return {a.y*b.z - a.z*b.y, a.z*b.x - a.x*b.z, a.x*b.y - a.y*b.x};
}
__device__ inline F3 norm3(F3 v) {
    float s = dot3(v, v);
    float inv = 1.0f / sqrtf(fmaxf(s, EPS));
    return scale3(v, inv);
}

__device__ inline float block_reduce_sum(float v, float* red) {
    for (int o = 32; o > 0; o >>= 1) v += __shfl_down(v, o, 64);
    int wave = threadIdx.x >> 6, lane = threadIdx.x & 63;
    int nw = blockDim.x >> 6;
    __syncthreads();
    if (lane == 0) red[wave] = v;
    __syncthreads();
    float s = 0.f;
    if (threadIdx.x == 0) for (int w = 0; w < nw; w++) s += red[w];
    return s;
}

// ---------------- frames ----------------
// idx in [0, L*N): pred frame (l=idx/N, i=idx%N). idx in [L*N,(L+1)*N): gt frame,
// also packs maskbits|batch|chain into packed[i].
__global__ __launch_bounds__(256) void frames_kernel(
    const float* __restrict__ pred, const float* __restrict__ gt,
    const float* __restrict__ atom_mask,
    const int* __restrict__ batch, const int* __restrict__ chain,
    float* __restrict__ framesP, float* __restrict__ framesG,
    int* __restrict__ packed, float* __restrict__ acc,
    int L, int N, int A)
{
    int idx = blockIdx.x * blockDim.x + threadIdx.x;
    if (idx == 0) {
        for (int k = 0; k < 8; k++) acc[k] = 0.f;  // ws is poisoned; zero accumulators
    }
    int total = (L + 1) * N;
    if (idx >= total) return;

    const float* base;
    float* outF;
    if (idx < L * N) {
        base = pred + (size_t)idx * A * 3;
        outF = framesP + (size_t)idx * 12;
    } else {
        int i = idx - L * N;
        base = gt + (size_t)i * A * 3;
        outF = framesG + (size_t)i * 12;
        unsigned m = 0;
        for (int a = 0; a < A; a++)
            if (atom_mask[(size_t)i * A + a] > 0.f) m |= (1u << a);
        packed[i] = (int)(m | ((unsigned)batch[i] << 16) | ((unsigned)chain[i] << 24));
    }
    F3 n  = {base[0], base[1], base[2]};
    F3 ca = {base[3], base[4], base[5]};
    F3 c  = {base[6], base[7], base[8]};
    F3 e1 = norm3(sub3(c, ca));
    F3 v2 = sub3(n, ca);
    float d = dot3(e1, v2);
    F3 e2 = norm3({v2.x - d*e1.x, v2.y - d*e1.y, v2.z - d*e1.z});
    F3 e3 = cross3(e1, e2);
    outF[0] = e1.x; outF[1] = e1.y; outF[2] = e1.z;
    outF[3] = e2.x; outF[4] = e2.y; outF[5] = e2.z;
    outF[6] = e3.x; outF[7] = e3.y; outF[8] = e3.z;
    outF[9] = ca.x; outF[10] = ca.y; outF[11] = ca.z;
}

// ---------------- fape core (+ fused lddt on last layer) ----------------
// |Rp^T(x-tp) - Rg^T(y-tg)| == |(x-tp) - M(y-tg)|, M = Rp·Rg^T (Rp orthogonal).
// So per atom: d = x - (M·y + c), c = tp - M·tg. One 3x3 transform, not two.
template<int AT>
__global__ __launch_bounds__(256) void fape_kernel(
    const float* __restrict__ pred, const float* __restrict__ gt,
    const float* __restrict__ framesP, const float* __restrict__ framesG,
    const int* __restrict__ packed,
    float* __restrict__ diag, float* __restrict__ acc,
    float* __restrict__ out_final, float* __restrict__ out_rot,
    float* __restrict__ out_lddt,
    int L, int N, int A)
{
    int b = blockIdx.x;
    int l = b / N;
    int i = b - l * N;
    const float* fP = framesP + (size_t)b * 12;
    const float* fG = framesG + (size_t)i * 12;

    float p00 = fP[0], p01 = fP[1], p02 = fP[2];
    float p10 = fP[3], p11 = fP[4], p12 = fP[5];
    float p20 = fP[6], p21 = fP[7], p22 = fP[8];
    float cpx = fP[9], cpy = fP[10], cpz = fP[11];
    float g00 = fG[0], g01 = fG[1], g02 = fG[2];
    float g10 = fG[3], g11 = fG[4], g12 = fG[5];
    float g20 = fG[6], g21 = fG[7], g22 = fG[8];
    float cgx = fG[9], cgy = fG[10], cgz = fG[11];

    // M = e1p⊗e1g + e2p⊗e2g + e3p⊗e3g   (M[d][e] = Σ_k ekp[d]·ekg[e])
    float m00 = p00*g00 + p10*g10 + p20*g20;
    float m01 = p00*g01 + p10*g11 + p20*g21;
    float m02 = p00*g02 + p10*g12 + p20*g22;
    float m10 = p01*g00 + p11*g10 + p21*g20;
    float m11 = p01*g01 + p11*g11 + p21*g21;
    float m12 = p01*g02 + p11*g12 + p21*g22;
    float m20 = p02*g00 + p12*g10 + p22*g20;
    float m21 = p02*g01 + p12*g11 + p22*g21;
    float m22 = p02*g02 + p12*g12 + p22*g22;
    // c = tp - M·tg
    float c0 = cpx - (m00*cgx + m01*cgy + m02*cgz);
    float c1 = cpy - (m10*cgx + m11*cgy + m12*cgz);
    float c2 = cpz - (m20*cgx + m21*cgy + m22*cgz);

    int pki = packed[i];
    int mi = pki & 0xFFFF;
    int bi = (pki >> 16) & 0xFF;
    int ci = (pki >> 24) & 0xFF;
    bool last = (l == L - 1);
    bool rmi = (mi != 0);

    float s_same = 0.f, s_other = 0.f, c_same = 0.f, c_other = 0.f;
    float l_sum = 0.f, l_cnt = 0.f;

    const int AR = (AT > 0) ? AT : 1;  // compile-time atom count (AT>0 path)

    for (int j = threadIdx.x; j < N; j += blockDim.x) {
        int pkj = packed[j];
        float fv = 0.f;
        bool pm2 = false, samec = false;
        if (((pkj >> 16) & 0xFF) == bi) {
            int mj = mi & (pkj & 0xFFFF);
            if (mj) {
                pm2 = true;
                samec = (((pkj >> 24) & 0xFF) == ci);
                float num = 0.f;
                const float2* x2 = (const float2*)(pred + (((size_t)l * N + j) * A) * 3);
                const float2* y2 = (const float2*)(gt + ((size_t)j * A) * 3);
                if (AT > 0) {
                    // unconditional vector loads; mask applied as multiplier
                    #pragma unroll
                    for (int t = 0; t < AR / 2; t++) {
                        float2 xa = x2[3*t], xb = x2[3*t+1], xc = x2[3*t+2];
                        float2 ya = y2[3*t], yb = y2[3*t+1], yc = y2[3*t+2];
                        // atom 2t
                        {
                            float d0 = xa.x - (m00*ya.x + m01*ya.y + m02*yb.x + c0);
                            float d1 = xa.y - (m10*ya.x + m11*ya.y + m12*yb.x + c1);
                            float d2 = xb.x - (m20*ya.x + m21*ya.y + m22*yb.x + c2);
                            float s = d0*d0 + d1*d1 + d2*d2;
                            float w = (float)((mj >> (2*t)) & 1);
                            num += w * sqrtf(fmaxf(s, EPS));
                        }
                        // atom 2t+1
                        {
                            float d0 = xb.y - (m00*yb.y + m01*yc.x + m02*yc.y + c0);
                            float d1 = xc.x - (m10*yb.y + m11*yc.x + m12*yc.y + c1);
                            float d2 = xc.y - (m20*yb.y + m21*yc.x + m22*yc.y + c2);
                            float s = d0*d0 + d1*d1 + d2*d2;
                            float w = (float)((mj >> (2*t+1)) & 1);
                            num += w * sqrtf(fmaxf(s, EPS));
                        }
                    }
                } else {
                    const float* xb = (const float*)x2;
                    const float* yb = (const float*)y2;
                    for (int a = 0; a < A; a++) {
                        float x0 = xb[a*3+0], x1 = xb[a*3+1], xv2 = xb[a*3+2];
                        float y0 = yb[a*3+0], y1 = yb[a*3+1], yv2 = yb[a*3+2];
                        float d0 = x0 - (m00*y0 + m01*y1 + m02*yv2 + c0);
                        float d1 = x1 - (m10*y0 + m11*y1 + m12*yv2 + c1);
                        float d2 = xv2 - (m20*y0 + m21*y1 + m22*yv2 + c2);
                        float s = d0*d0 + d1*d1 + d2*d2;
                        float w = (float)((mj >> a) & 1);
                        num += w * sqrtf(fmaxf(s, EPS));
                    }
                }
                fv = num / (float)__popc((unsigned)mj);
            }
        }
        if (last) {
            out_final[(size_t)i * N + j] = fv;
            // fused lddt (no batch condition in reference dmask)
            if (rmi && j != i && (pkj & 0xFFFF) != 0) {
                float dx = cgx - fG[0];  // placeholder, replaced below
                (void)dx;
            }
        }
        if (j == i) {
            diag[b] = fv;
            if (last) out_rot[i] = fv;
        }
        float cl = fminf(fv, 10.f);
        if (pm2) {
            if (samec) { s_same += cl; c_same += 1.f; }
            else       { s_other += cl; c_other += 1.f; }
        }
        // ---- lddt contribution (last layer only) ----
        if (last && rmi && j != i && (pkj & 0xFFFF) != 0) {
            const float* fGj = framesG + (size_t)j * 12;
            const float* fPj = framesP + ((size_t)(L-1) * N + j) * 12;
            float dx = cgx - fGj[9], dy = cgy - fGj[10], dz = cgz - fGj[11];
            float gd = sqrtf(fmaxf(dx*dx + dy*dy + dz*dz, EPS));
            if (gd < 15.f) {
                float ex = cpx - fPj[9], ey = cpy - fPj[10], ez = cpz - fPj[11];
                float pd = sqrtf(fmaxf(ex*ex + ey*ey + ez*ez, EPS));
                float de = fabsf(gd - pd);
                float lv = ((de < 0.5f ? 1.f : 0.f) + (de < 1.f ? 1.f : 0.f) +
                            (de < 2.f ? 1.f : 0.f) + (de < 4.f ? 1.f : 0.f)) * 0.25f;
                l_sum += lv;
                l_cnt += 1.f;
            }
        }
    }

    // block reduce 6 values
    for (int o = 32; o > 0; o >>= 1) {
        s_same  += __shfl_down(s_same, o, 64);
        s_other += __shfl_down(s_other, o, 64);
        c_same  += __shfl_down(c_same, o, 64);
        c_other += __shfl_down(c_other, o, 64);
        l_sum   += __shfl_down(l_sum, o, 64);
        l_cnt   += __shfl_down(l_cnt, o, 64);
    }
    __shared__ float red[4][6];
    int wave = threadIdx.x >> 6, lane = threadIdx.x & 63;
    if (lane == 0) {
        red[wave][0] = s_same; red[wave][1] = s_other;
        red[wave][2] = c_same; red[wave][3] = c_other;
        red[wave][4] = l_sum;  red[wave][5] = l_cnt;
    }
    __syncthreads();
    if (threadIdx.x == 0) {
        float ss = 0, so = 0, cs = 0, co = 0, ls = 0, lc = 0;
        int nw = blockDim.x >> 6;
        for (int w = 0; w < nw; w++) {
            ss += red[w][0]; so += red[w][1]; cs += red[w][2];
            co += red[w][3]; ls += red[w][4]; lc += red[w][5];
        }
        atomicAdd(&acc[l], ss);
        atomicAdd(&acc[L + l], so);
        if (l == 0) {
            atomicAdd(&acc[2 * L], cs);
            atomicAdd(&acc[2 * L + 1], co);
        }
        if (last) out_lddt[i] = ls / fmaxf(lc, 1e-6f);
    }
}

// ---------------- finalize scalars ----------------
__global__ __launch_bounds__(256) void finalize_kernel(
    const int* __restrict__ packed, const float* __restrict__ diag,
    const float* __restrict__ acc, float* __restrict__ out, int L, int N)
{
    __shared__ float red[8];
    float nr = 0.f;
    for (int i = threadIdx.x; i < N; i += blockDim.x)
        nr += ((packed[i] & 0xFFFF) != 0) ? 1.f : 0.f;
    float n_res = block_reduce_sum(nr, red);

    float rs[4];  // assumes L <= 4
    for (int l = 0; l < L; l++) {
        float s = 0.f;
        for (int i = threadIdx.x; i < N; i += blockDim.x)
            s += diag[(size_t)l * N + i];
        rs[l] = block_reduce_sum(s, red);
    }
    if (threadIdx.x == 0) {
        float cs = fmaxf(acc[2 * L], 1e-6f);
        float co = fmaxf(acc[2 * L + 1], 1e-6f);
        float nrm = fmaxf(n_res, 1e-6f);
        for (int l = 0; l < L; l++) {
            out[l]     = acc[l] / cs / 10.f + acc[L + l] / co / 10.f;
            out[L + l] = rs[l] / nrm;
        }
    }
}

extern "C" void kernel_launch(void* const* d_in, const int* in_sizes, int n_in,
                              void* d_out, int out_size, void* d_ws, size_t ws_size,
                              hipStream_t stream)
{
    const float* pred      = (const float*)d_in[0];
    const float* gt        = (const float*)d_in[1];
    const float* atom_mask = (const float*)d_in[2];
    const int*   batch     = (const int*)d_in[3];
    const int*   chain     = (const int*)d_in[4];

    int N = in_sizes[3];
    int A = in_sizes[2] / N;
    int L = in_sizes[0] / (N * A * 3);

    float* out = (float*)d_out;
    float* out_final = out + 2 * L;
    float* out_rot   = out_final + (size_t)N * N;
    float* out_lddt  = out_rot + N;

    float* ws = (float*)d_ws;
    float* framesP = ws;                              // L*N*12
    float* framesG = framesP + (size_t)L * N * 12;    // N*12
    float* diag    = framesG + (size_t)N * 12;        // L*N
    float* acc     = diag + (size_t)L * N;            // 8
    int*   packed  = (int*)(acc + 8);                 // N

    int totalF = (L + 1) * N;
    frames_kernel<<<(totalF + 255) / 256, 256, 0, stream>>>(
        pred, gt, atom_mask, batch, chain, framesP, framesG, packed, acc, L, N, A);
    if (A == 14) {
        fape_kernel<14><<<L * N, 256, 0, stream>>>(
            pred, gt, framesP, framesG, packed,
            diag, acc, out_final, out_rot, out_lddt, L, N, A);
    } else {
        fape_kernel<0><<<L * N, 256, 0, stream>>>(
            pred, gt, framesP, framesG, packed,
            diag, acc, out_final, out_rot, out_lddt, L, N, A);
    }
    finalize_kernel<<<1, 256, 0, stream>>>(packed, diag, acc, out, L, N);
}

// Round 3
// 162.430 us; speedup vs baseline: 1.0996x; 1.0027x over previous
//
#include <hip/hip_runtime.h>
#include <math.h>

#define EPS 1e-6f
#define IBLK 6
#define CHUNK 64

struct F3 { float x, y, z; };
__device__ inline F3 sub3(F3 a, F3 b){return {a.x-b.x,a.y-b.y,a.z-b.z};}
__device__ inline float dot3(F3 a, F3 b){return a.x*b.x+a.y*b.y+a.z*b.z;}
__device__ inline F3 scale3(F3 a,float s){return {a.x*s,a.y*s,a.z*s};}
__device__ inline F3 cross3(F3 a,F3 b){return {a.y*b.z-a.z*b.y, a.z*b.x-a.x*b.z, a.x*b.y-a.y*b.x};}
__device__ inline F3 norm3(F3 v){float s=dot3(v,v);float inv=1.f/sqrtf(fmaxf(s,EPS));return scale3(v,inv);}

__device__ inline void make_frame(const float* __restrict__ base, float R[9], F3& ca) {
    F3 n = {base[0], base[1], base[2]};
    ca   = {base[3], base[4], base[5]};
    F3 c = {base[6], base[7], base[8]};
    F3 e1 = norm3(sub3(c, ca));
    F3 v2 = sub3(n, ca);
    float d = dot3(e1, v2);
    F3 e2 = norm3({v2.x - d*e1.x, v2.y - d*e1.y, v2.z - d*e1.z});
    F3 e3 = cross3(e1, e2);
    R[0]=e1.x; R[1]=e1.y; R[2]=e1.z;
    R[3]=e2.x; R[4]=e2.y; R[5]=e2.z;
    R[6]=e3.x; R[7]=e3.y; R[8]=e3.z;
}

// ---------------- prep: frames -> fused M,c per (l,i); packed; CA arrays; zero accums ----
__global__ __launch_bounds__(256) void prep_kernel(
    const float* __restrict__ pred, const float* __restrict__ gt,
    const float* __restrict__ atom_mask, const int* __restrict__ batch,
    const int* __restrict__ chain,
    float* __restrict__ Mc, int* __restrict__ packed,
    float* __restrict__ gtca, float* __restrict__ predca,
    float* __restrict__ lddt_s, float* __restrict__ lddt_c,
    float* __restrict__ acc, unsigned int* __restrict__ counter,
    int L, int N, int A)
{
    int idx = blockIdx.x * blockDim.x + threadIdx.x;
    if (idx == 0) { for (int k = 0; k < 8; k++) acc[k] = 0.f; *counter = 0u; }
    if (idx >= L * N) return;
    int l = idx / N, i = idx - l * N;

    float Rg[9]; F3 cag;
    make_frame(gt + (size_t)i * A * 3, Rg, cag);
    float Rp[9]; F3 cap;
    make_frame(pred + ((size_t)l * N + i) * A * 3, Rp, cap);

    // M[d][e] = sum_k Rp[k*3+d] * Rg[k*3+e]   (M = Rp^T_rows · ... = Rp·Rg^T fused form)
    float m[9];
    #pragma unroll
    for (int d = 0; d < 3; d++)
        #pragma unroll
        for (int e = 0; e < 3; e++)
            m[d*3+e] = Rp[0*3+d]*Rg[0*3+e] + Rp[1*3+d]*Rg[1*3+e] + Rp[2*3+d]*Rg[2*3+e];
    float c0 = cap.x - (m[0]*cag.x + m[1]*cag.y + m[2]*cag.z);
    float c1 = cap.y - (m[3]*cag.x + m[4]*cag.y + m[5]*cag.z);
    float c2 = cap.z - (m[6]*cag.x + m[7]*cag.y + m[8]*cag.z);

    float* o = Mc + (size_t)idx * 12;
    #pragma unroll
    for (int k = 0; k < 9; k++) o[k] = m[k];
    o[9] = c0; o[10] = c1; o[11] = c2;

    if (l == 0) {
        unsigned mm = 0;
        for (int a = 0; a < A; a++)
            if (atom_mask[(size_t)i * A + a] > 0.f) mm |= (1u << a);
        packed[i] = (int)(mm | ((unsigned)batch[i] << 16) | ((unsigned)chain[i] << 24));
        gtca[i*3] = cag.x; gtca[i*3+1] = cag.y; gtca[i*3+2] = cag.z;
        lddt_s[i] = 0.f; lddt_c[i] = 0.f;
    }
    if (l == L - 1) { predca[i*3] = cap.x; predca[i*3+1] = cap.y; predca[i*3+2] = cap.z; }
}

// ---------------- mega: thread owns j (row in regs), block loops i; fused lddt + finalize ----
__global__ __launch_bounds__(256, 3) void fape_mega(
    const float* __restrict__ pred, const float* __restrict__ gt,
    const float* __restrict__ Mc, const int* __restrict__ packed,
    const float* __restrict__ gtca, const float* __restrict__ predca,
    float* __restrict__ acc,
    float* __restrict__ lddt_s, float* __restrict__ lddt_c,
    unsigned int* __restrict__ counter,
    float* __restrict__ out, float* __restrict__ out_final,
    float* __restrict__ out_rot, float* __restrict__ out_lddt,
    int L, int N, int gridTotal)
{
    __shared__ float smem[CHUNK * 85];   // 64 rows x (42 pred | 42 gt | 1 pad)
    __shared__ float red[4][5];
    __shared__ float redf[4];
    __shared__ int flag;

    int t  = threadIdx.x;
    int it = blockIdx.x, jt = blockIdx.y, l = blockIdx.z;
    int j  = jt * 256 + t;
    int i0 = it * IBLK;
    bool last = (l == L - 1);

    int pkj = packed[j];
    int mjs = pkj & 0xFFFF;
    int bj  = (pkj >> 16) & 0xFF;
    int cjc = (pkj >> 24) & 0xFF;

    // ---- Phase B: coalesced global -> LDS bounce -> per-thread registers ----
    float x[42], y[42];
    const float* psrc = pred + ((size_t)l * N + (size_t)jt * 256) * 42;
    const float* gsrc = gt + ((size_t)jt * 256) * 42;
    for (int c = 0; c < 4; c++) {
        __syncthreads();
        for (int w = t; w < CHUNK * 42; w += 256) {
            int r = w / 42, cc = w - r * 42;
            smem[r * 85 + cc]      = psrc[(size_t)c * CHUNK * 42 + w];
            smem[r * 85 + 42 + cc] = gsrc[(size_t)c * CHUNK * 42 + w];
        }
        __syncthreads();
        if ((t >> 6) == c) {
            int base = (t & 63) * 85;
            #pragma unroll
            for (int k = 0; k < 42; k++) { x[k] = smem[base + k]; y[k] = smem[base + 42 + k]; }
        }
    }

    // ---- Phase C: loop over i (uniform per block) ----
    float s_same = 0.f, s_other = 0.f, c_same = 0.f, c_other = 0.f, rot = 0.f;
    for (int ii = 0; ii < IBLK; ii++) {
        int i = i0 + ii;
        int pki = packed[i];                     // uniform -> scalar load
        const float* mc = Mc + ((size_t)l * N + i) * 12;
        float m00 = mc[0], m01 = mc[1], m02 = mc[2];
        float m10 = mc[3], m11 = mc[4], m12 = mc[5];
        float m20 = mc[6], m21 = mc[7], m22 = mc[8];
        float c0 = mc[9], c1 = mc[10], c2 = mc[11];
        int mi = pki & 0xFFFF;
        int bi = (pki >> 16) & 0xFF, ci = (pki >> 24) & 0xFF;

        int mj = mi & mjs;
        bool pm2 = (bj == bi) && (mj != 0);
        float fv = 0.f;
        if (__any(pm2)) {
            float num = 0.f;
            #pragma unroll
            for (int a = 0; a < 14; a++) {
                float y0 = y[a*3], y1 = y[a*3+1], y2v = y[a*3+2];
                float d0 = x[a*3]   - (m00*y0 + m01*y1 + m02*y2v + c0);
                float d1 = x[a*3+1] - (m10*y0 + m11*y1 + m12*y2v + c1);
                float d2 = x[a*3+2] - (m20*y0 + m21*y1 + m22*y2v + c2);
                float s = d0*d0 + d1*d1 + d2*d2;
                float w = (float)((mj >> a) & 1);
                num += w * sqrtf(fmaxf(s, EPS));
            }
            fv = pm2 ? num / (float)__popc((unsigned)mj) : 0.f;
        }
        if (last) out_final[(size_t)i * N + j] = fv;   // coalesced
        if (j == i) {
            rot += fv;
            if (last) out_rot[i] = fv;
        }
        if (pm2) {
            float cl = fminf(fv, 10.f);
            if (ci == cjc) { s_same += cl;  c_same += 1.f; }
            else           { s_other += cl; c_other += 1.f; }
        }
        if (last) {
            bool ok = (mi != 0) && (mjs != 0) && (j != i);
            if (__any(ok)) {
                float ls = 0.f, lc = 0.f;
                float dx = gtca[i*3] - y[3], dy = gtca[i*3+1] - y[4], dz = gtca[i*3+2] - y[5];
                float gd = sqrtf(fmaxf(dx*dx + dy*dy + dz*dz, EPS));
                if (ok && gd < 15.f) {
                    float ex = predca[i*3] - x[3], ey = predca[i*3+1] - x[4], ez = predca[i*3+2] - x[5];
                    float pd = sqrtf(fmaxf(ex*ex + ey*ey + ez*ez, EPS));
                    float de = fabsf(gd - pd);
                    ls = ((de < 0.5f ? 1.f : 0.f) + (de < 1.f ? 1.f : 0.f) +
                          (de < 2.f ? 1.f : 0.f) + (de < 4.f ? 1.f : 0.f)) * 0.25f;
                    lc = 1.f;
                }
                for (int o = 32; o > 0; o >>= 1) {
                    ls += __shfl_down(ls, o, 64);
                    lc += __shfl_down(lc, o, 64);
                }
                if ((t & 63) == 0) {
                    atomicAdd(&lddt_s[i], ls);
                    atomicAdd(&lddt_c[i], lc);
                }
            }
        }
    }

    // ---- block reduce 5 accumulators -> global atomics ----
    for (int o = 32; o > 0; o >>= 1) {
        s_same  += __shfl_down(s_same, o, 64);
        s_other += __shfl_down(s_other, o, 64);
        c_same  += __shfl_down(c_same, o, 64);
        c_other += __shfl_down(c_other, o, 64);
        rot     += __shfl_down(rot, o, 64);
    }
    int wave = t >> 6, lane = t & 63;
    if (lane == 0) {
        red[wave][0] = s_same; red[wave][1] = s_other;
        red[wave][2] = c_same; red[wave][3] = c_other; red[wave][4] = rot;
    }
    __syncthreads();
    if (t == 0) {
        float ss = 0, so = 0, cs = 0, co = 0, rt = 0;
        for (int w = 0; w < 4; w++) {
            ss += red[w][0]; so += red[w][1]; cs += red[w][2];
            co += red[w][3]; rt += red[w][4];
        }
        atomicAdd(&acc[l], ss);
        atomicAdd(&acc[L + l], so);
        if (l == 0) {
            atomicAdd(&acc[2 * L], cs);
            atomicAdd(&acc[2 * L + 1], co);
        }
        atomicAdd(&acc[2 * L + 2 + l], rt);
    }

    // ---- ticket: last block to finish does the finalize ----
    __threadfence();
    if (t == 0) {
        unsigned tk = atomicAdd(counter, 1u);
        flag = (tk == (unsigned)(gridTotal - 1)) ? 1 : 0;
    }
    __syncthreads();
    if (flag) {
        __threadfence();
        for (int i2 = t; i2 < N; i2 += 256)
            out_lddt[i2] = lddt_s[i2] / fmaxf(lddt_c[i2], 1e-6f);
        float nr = 0.f;
        for (int i2 = t; i2 < N; i2 += 256)
            nr += ((packed[i2] & 0xFFFF) != 0) ? 1.f : 0.f;
        for (int o = 32; o > 0; o >>= 1) nr += __shfl_down(nr, o, 64);
        __syncthreads();
        if (lane == 0) redf[wave] = nr;
        __syncthreads();
        if (t == 0) {
            float n_res = redf[0] + redf[1] + redf[2] + redf[3];
            float cs = fmaxf(acc[2 * L], 1e-6f);
            float co = fmaxf(acc[2 * L + 1], 1e-6f);
            float nrm = fmaxf(n_res, 1e-6f);
            for (int l2 = 0; l2 < L; l2++) {
                out[l2]     = acc[l2] / cs / 10.f + acc[L + l2] / co / 10.f;
                out[L + l2] = acc[2 * L + 2 + l2] / nrm;
            }
        }
    }
}

extern "C" void kernel_launch(void* const* d_in, const int* in_sizes, int n_in,
                              void* d_out, int out_size, void* d_ws, size_t ws_size,
                              hipStream_t stream)
{
    const float* pred      = (const float*)d_in[0];
    const float* gt        = (const float*)d_in[1];
    const float* atom_mask = (const float*)d_in[2];
    const int*   batch     = (const int*)d_in[3];
    const int*   chain     = (const int*)d_in[4];

    int N = in_sizes[3];
    int A = in_sizes[2] / N;
    int L = in_sizes[0] / (N * A * 3);

    float* out = (float*)d_out;
    float* out_final = out + 2 * L;
    float* out_rot   = out_final + (size_t)N * N;
    float* out_lddt  = out_rot + N;

    float* ws = (float*)d_ws;
    float* Mc      = ws;                                  // L*N*12
    float* gtca    = Mc + (size_t)L * N * 12;             // N*3
    float* predca  = gtca + (size_t)N * 3;                // N*3
    float* lddt_s  = predca + (size_t)N * 3;              // N
    float* lddt_c  = lddt_s + N;                          // N
    float* acc     = lddt_c + N;                          // 8
    unsigned int* counter = (unsigned int*)(acc + 8);     // 1
    int* packed    = (int*)(counter + 1);                 // N

    int totalP = L * N;
    prep_kernel<<<(totalP + 255) / 256, 256, 0, stream>>>(
        pred, gt, atom_mask, batch, chain,
        Mc, packed, gtca, predca, lddt_s, lddt_c, acc, counter, L, N, A);

    int IT = N / IBLK;        // 128
    int JT = N / 256;         // 3
    dim3 grid(IT, JT, L);     // 768 blocks
    int gridTotal = IT * JT * L;
    fape_mega<<<grid, 256, 0, stream>>>(
        pred, gt, Mc, packed, gtca, predca,
        acc, lddt_s, lddt_c, counter,
        out, out_final, out_rot, out_lddt, L, N, gridTotal);
}